// Round 13
// baseline (264.784 us; speedup 1.0000x reference)
//
#include <hip/hip_runtime.h>
#include <hip/hip_bf16.h>

#define D_MODELC 1024
#define D_FFC    4096
#define N_HEADSC 16
#define BATCHC   2
#define SEQC     2048
#define M_TOK    (BATCHC*SEQC)   // 4096

typedef __attribute__((ext_vector_type(4)))  float f32x4;
typedef __attribute__((ext_vector_type(16))) float f32x16;
typedef __attribute__((ext_vector_type(8)))  short s16x8;
using bf16_t = __hip_bfloat16;

static __device__ __forceinline__ unsigned short f2bf_u16(float f) {
  bf16_t h = __float2bfloat16(f);
  return __builtin_bit_cast(unsigned short, h);
}

static __device__ __forceinline__ unsigned int cvt_pk_bf16(float lo, float hi2) {
  unsigned int r;
  asm("v_cvt_pk_bf16_f32 %0, %1, %2" : "=v"(r) : "v"(lo), "v"(hi2));
  return r;
}

#define PSWAP(a, b) asm volatile("v_permlane32_swap_b32 %0, %1" : "+v"(a), "+v"(b))

#define ASYNC_COPY16(dst_lds, src_g) \
  __builtin_amdgcn_global_load_lds((const __attribute__((address_space(1))) void*)(src_g), \
                                   (__attribute__((address_space(3))) void*)(dst_lds), 16, 0, 0)

// ---------------- fused prep: 4x 1024^2 transpose + W1^T + W2^T + x->bf16 + bias pack ----
__global__ __launch_bounds__(256) void k_prep(
    const float* __restrict__ x,
    const float* __restrict__ Wq, const float* __restrict__ Wk,
    const float* __restrict__ Wv, const float* __restrict__ Wo,
    const float* __restrict__ W1, const float* __restrict__ W2,
    const float* __restrict__ bq, const float* __restrict__ bk,
    const float* __restrict__ bv,
    bf16_t* __restrict__ x16, bf16_t* __restrict__ wqkvT, bf16_t* __restrict__ woT,
    bf16_t* __restrict__ w1T, bf16_t* __restrict__ w2T, float* __restrict__ bqkv) {
  __shared__ float tile[32][33];
  const int bidx = blockIdx.x;
  const int tid = threadIdx.x;

  if (bidx < 12288) {
    const float* in;
    bf16_t* out;
    int R, C, bx, by;
    if (bidx < 4096) {
      const int z = bidx >> 10, t = bidx & 1023;
      in = (z == 0) ? Wq : (z == 1) ? Wk : (z == 2) ? Wv : Wo;
      out = (z == 0) ? wqkvT : (z == 1) ? wqkvT + 1024 * 1024
           : (z == 2) ? wqkvT + 2 * 1024 * 1024 : woT;
      R = 1024; C = 1024; bx = t & 31; by = t >> 5;
    } else if (bidx < 8192) {
      const int t = bidx - 4096;
      in = W1; out = w1T; R = 1024; C = 4096; bx = t & 127; by = t >> 7;
    } else {
      const int t = bidx - 8192;
      in = W2; out = w2T; R = 4096; C = 1024; bx = t & 31; by = t >> 5;
    }
    const int tx = tid & 31, ty = tid >> 5;
    const int c0 = bx * 32, r0 = by * 32;
#pragma unroll
    for (int i = 0; i < 4; ++i)
      tile[ty + i * 8][tx] = in[(size_t)(r0 + ty + i * 8) * C + c0 + tx];
    __syncthreads();
#pragma unroll
    for (int i = 0; i < 4; ++i)
      out[(size_t)(c0 + ty + i * 8) * R + r0 + tx] = __float2bfloat16(tile[tx][ty + i * 8]);
  } else if (bidx < 16384) {
    const int i = (bidx - 12288) * 256 + tid;
    float4 v = ((const float4*)x)[i];
    short4 o;
    o.x = (short)f2bf_u16(v.x);
    o.y = (short)f2bf_u16(v.y);
    o.z = (short)f2bf_u16(v.z);
    o.w = (short)f2bf_u16(v.w);
    ((short4*)x16)[i] = o;
  } else {
    const int i = (bidx - 16384) * 256 + tid;
    float v = (i < 1024) ? bq[i] : (i < 2048) ? bk[i - 1024] : bv[i - 2048];
    bqkv[i] = v;
  }
}

// ---------------- GEMM 256x256, BK=64, deep pipeline w/ counted vmcnt (T3+T4+T5) --------
__global__ __launch_bounds__(512, 2) void k_gemm256(
    const bf16_t* __restrict__ A, const bf16_t* __restrict__ BT,
    const float* __restrict__ bias, bf16_t* __restrict__ Cout,
    int N, int K, int lda, int ldb, int ldc, int mode) {
  __shared__ __align__(16) bf16_t Ab[2][256][64];
  __shared__ __align__(16) bf16_t Bb[2][256][64];

  const int nbn = N / 256;
  const int nwg = gridDim.x;
  const int cpx = nwg >> 3;
  const int wg = (blockIdx.x & 7) * cpx + (blockIdx.x >> 3);  // XCD swizzle (nwg%8==0)
  const int mb = wg / nbn, nb = wg % nbn;
  const int row0 = mb * 256, col0 = nb * 256;

  const int tid = threadIdx.x;
  const int w = tid >> 6, lane = tid & 63;
  const int lr = lane & 15, lg = lane >> 4;
  const int wr = w >> 2, wc = w & 3;
  const int s7 = lr & 7;

#define STAGE256(buf, kt_)                                                            \
  {                                                                                   \
    const int k0_ = (kt_) * 64;                                                       \
    _Pragma("unroll")                                                                 \
    for (int i_ = 0; i_ < 4; ++i_) {                                                  \
      int c_ = tid + i_ * 512;                                                        \
      int row_ = c_ >> 3, sg_ = (c_ & 7) ^ (row_ & 7);                                \
      ASYNC_COPY16(&Ab[buf][0][0] + (size_t)c_ * 8,                                   \
                   A + (size_t)(row0 + row_) * lda + k0_ + sg_ * 8);                  \
    }                                                                                 \
    _Pragma("unroll")                                                                 \
    for (int i_ = 0; i_ < 4; ++i_) {                                                  \
      int c_ = tid + i_ * 512;                                                        \
      int row_ = c_ >> 3, sg_ = (c_ & 7) ^ (row_ & 7);                                \
      ASYNC_COPY16(&Bb[buf][0][0] + (size_t)c_ * 8,                                   \
                   BT + (size_t)(col0 + row_) * ldb + k0_ + sg_ * 8);                 \
    }                                                                                 \
  }

  f32x4 acc[8][4];
#pragma unroll
  for (int m = 0; m < 8; ++m)
#pragma unroll
    for (int n = 0; n < 4; ++n) acc[m][n] = (f32x4){0.f, 0.f, 0.f, 0.f};

  const int nt = K / 64;
  STAGE256(0, 0)
  STAGE256(1, 1)
  asm volatile("s_waitcnt vmcnt(8)" ::: "memory");
  __builtin_amdgcn_sched_barrier(0);
  __builtin_amdgcn_s_barrier();

  for (int t = 0; t < nt; ++t) {
    const int cur = t & 1;
    s16x8 a0[8], b0[4];
#pragma unroll
    for (int m = 0; m < 8; ++m)
      a0[m] = *(const s16x8*)(&Ab[cur][wr * 128 + m * 16 + lr][(lg ^ s7) * 8]);
#pragma unroll
    for (int n = 0; n < 4; ++n)
      b0[n] = *(const s16x8*)(&Bb[cur][wc * 64 + n * 16 + lr][(lg ^ s7) * 8]);
    __builtin_amdgcn_s_setprio(1);
#pragma unroll
    for (int m = 0; m < 8; ++m)
#pragma unroll
      for (int n = 0; n < 4; ++n)
        acc[m][n] = __builtin_amdgcn_mfma_f32_16x16x32_bf16(a0[m], b0[n], acc[m][n], 0, 0, 0);
    __builtin_amdgcn_s_setprio(0);
    s16x8 a1[8], b1[4];
#pragma unroll
    for (int m = 0; m < 8; ++m)
      a1[m] = *(const s16x8*)(&Ab[cur][wr * 128 + m * 16 + lr][((4 + lg) ^ s7) * 8]);
#pragma unroll
    for (int n = 0; n < 4; ++n)
      b1[n] = *(const s16x8*)(&Bb[cur][wc * 64 + n * 16 + lr][((4 + lg) ^ s7) * 8]);
    asm volatile("s_waitcnt lgkmcnt(0)" ::: "memory");
    __builtin_amdgcn_sched_barrier(0);
    __builtin_amdgcn_s_barrier();
    if (t + 2 < nt) STAGE256(cur, t + 2)
    __builtin_amdgcn_s_setprio(1);
#pragma unroll
    for (int m = 0; m < 8; ++m)
#pragma unroll
      for (int n = 0; n < 4; ++n)
        acc[m][n] = __builtin_amdgcn_mfma_f32_16x16x32_bf16(a1[m], b1[n], acc[m][n], 0, 0, 0);
    __builtin_amdgcn_s_setprio(0);
    if (t + 2 < nt) {
      asm volatile("s_waitcnt vmcnt(8)" ::: "memory");
    } else {
      asm volatile("s_waitcnt vmcnt(0)" ::: "memory");
    }
    __builtin_amdgcn_sched_barrier(0);
    __builtin_amdgcn_s_barrier();
  }

#pragma unroll
  for (int m = 0; m < 8; ++m) {
    int grow = row0 + wr * 128 + m * 16 + lg * 4;
#pragma unroll
    for (int n = 0; n < 4; ++n) {
      int gcol = col0 + wc * 64 + n * 16 + lr;
      float bv = bias[gcol];
      float cs = (mode == 3 && gcol < 1024) ? 0.18033688f : 1.f;  // 0.125*log2(e)
#pragma unroll
      for (int r = 0; r < 4; ++r) {
        float v = (acc[m][n][r] + bv) * cs;
        if (mode == 1) v = fmaxf(v, 0.f);
        Cout[(size_t)(grow + r) * ldc + gcol] = __float2bfloat16(v);
      }
    }
  }
#undef STAGE256
}

// ---------------- GEMM: 128x128 tile, BK=64, XOR-swizzled LDS, split-K (Wo/FF2) ---------
#define GBK 64

__global__ __launch_bounds__(256, 2) void k_gemm(
    const bf16_t* __restrict__ A, const bf16_t* __restrict__ BT,
    const float* __restrict__ bias,
    float* __restrict__ p0, float* __restrict__ p1,
    void* __restrict__ Cout, int M, int N, int K,
    int lda, int ldb, int ldc, int mode, int nsplit) {
  __shared__ __align__(16) bf16_t Asm[128 * GBK];
  __shared__ __align__(16) bf16_t Bsm[128 * GBK];

  const int nbn = N / 128;
  const int nwg = gridDim.x;
  const int cpx = nwg >> 3;
  int wg = (blockIdx.x & 7) * cpx + (blockIdx.x >> 3);  // XCD swizzle (nwg % 8 == 0)
  int kslice = 0;
  if (nsplit == 2) { kslice = wg & 1; wg >>= 1; }
  const int mb = wg / nbn, nb = wg % nbn;
  const int row0 = mb * 128, col0 = nb * 128;
  A  += (size_t)kslice * K;
  BT += (size_t)kslice * K;

  const int tid = threadIdx.x;
  const int w = tid >> 6, lane = tid & 63;
  const int lr = lane & 15, lg = lane >> 4;
  const int wr = w >> 1, wc = w & 1;
  const int wbase = tid & 192;

  f32x4 acc[4][4];
#pragma unroll
  for (int m = 0; m < 4; ++m)
#pragma unroll
    for (int n = 0; n < 4; ++n) acc[m][n] = (f32x4){0.f, 0.f, 0.f, 0.f};

  for (int k0 = 0; k0 < K; k0 += GBK) {
    __syncthreads();
#pragma unroll
    for (int i = 0; i < 4; ++i) {
      int c = i * 256 + tid;
      int row = c >> 3;
      int sg = (c & 7) ^ (row & 7);
      ASYNC_COPY16(Asm + (size_t)(i * 256 + wbase) * 8,
                   A + (size_t)(row0 + row) * lda + k0 + sg * 8);
    }
#pragma unroll
    for (int i = 0; i < 4; ++i) {
      int c = i * 256 + tid;
      int row = c >> 3;
      int sg = (c & 7) ^ (row & 7);
      ASYNC_COPY16(Bsm + (size_t)(i * 256 + wbase) * 8,
                   BT + (size_t)(col0 + row) * ldb + k0 + sg * 8);
    }
    __syncthreads();
#pragma unroll
    for (int kst = 0; kst < 2; ++kst) {
      const int sl = ((kst * 4 + lg) ^ (lr & 7)) * 8;
      s16x8 af[4], bfr[4];
#pragma unroll
      for (int m = 0; m < 4; ++m)
        af[m] = *(const s16x8*)(Asm + (size_t)(wr * 64 + m * 16 + lr) * GBK + sl);
#pragma unroll
      for (int n = 0; n < 4; ++n)
        bfr[n] = *(const s16x8*)(Bsm + (size_t)(wc * 64 + n * 16 + lr) * GBK + sl);
#pragma unroll
      for (int m = 0; m < 4; ++m)
#pragma unroll
        for (int n = 0; n < 4; ++n)
          acc[m][n] = __builtin_amdgcn_mfma_f32_16x16x32_bf16(af[m], bfr[n], acc[m][n], 0, 0, 0);
    }
  }

  float* outf = (kslice == 0) ? p0 : p1;
  bf16_t* outh = (bf16_t*)Cout;
#pragma unroll
  for (int m = 0; m < 4; ++m) {
    int grow = row0 + wr * 64 + m * 16 + lg * 4;
#pragma unroll
    for (int n = 0; n < 4; ++n) {
      int gcol = col0 + wc * 64 + n * 16 + lr;
      float bv = (mode == 4) ? 0.f : bias[gcol];
#pragma unroll
      for (int r = 0; r < 4; ++r) {
        float v = acc[m][n][r] + bv;
        size_t idx = (size_t)(grow + r) * ldc + gcol;
        if (mode == 4) {
          outf[idx] = v;
        } else {
          if (mode == 1) v = fmaxf(v, 0.f);
          outh[idx] = __float2bfloat16(v);
        }
      }
    }
  }
}

// ---------------- flash attention: 32x32 MFMA, K-split x2, bf16 partials ----------------
// XCD-group mapping: all 16 qt-blocks of one (half,b,h) group share blockIdx%8 (one XCD).
// Mask flag/values kept in registers (no LDS) -> LDS exactly 32 KB -> 5 blocks/CU.
__global__ __launch_bounds__(256, 5) void k_attn(
    const bf16_t* __restrict__ qkv, const int* __restrict__ mask,
    bf16_t* __restrict__ pA, bf16_t* __restrict__ pB,
    float* __restrict__ psA, float* __restrict__ psB) {
  const int bid = blockIdx.x;
  // bid = (j&7) | (qt<<3) | ((j>>3)<<7), j = (half<<5)|(b<<4)|h
  const int j = (bid & 7) + ((bid >> 7) << 3);
  const int qt = (bid >> 3) & 15;
  const int h = j & 15;
  const int b = (j >> 4) & 1;
  const int half = j >> 5;
  const int tid = threadIdx.x;
  const int w = tid >> 6, lane = tid & 63;
  const int l31 = lane & 31, hi = lane >> 5;
  const int wbase = tid & 192;

  __shared__ __align__(16) bf16_t Kl[2][64][64];   // XOR-swizzled (seg ^= row&7), 16 KB
  __shared__ __align__(16) bf16_t Vl[2][4096];     // tr-subtiled V, 16 KB

  const int tokb = b * SEQC;
  const int q0 = qt * 128 + w * 32;
  const int kb0 = half * (SEQC / 2);

  s16x8 qfrag[4];
  {
    const bf16_t* qp = qkv + (size_t)(tokb + q0 + l31) * 3072 + h * 64 + hi * 8;
#pragma unroll
    for (int s = 0; s < 4; ++s) qfrag[s] = *(const s16x8*)(qp + s * 16);
  }

  char* klc = (char*)&Kl[0][0][0];
  bf16_t* Vl0 = &Vl[0][0];
  const unsigned vbase =
      (unsigned)(size_t)(__attribute__((address_space(3))) bf16_t*)Vl0 + lane * 8;

  // hoisted staging source pointers (advance 64 tokens per tile)
  int vkey0, vd0, vkey1, vd1;
  {
    int c = tid, L = c >> 3;
    int f_ = L >> 4, t_ = (L >> 3) & 1, db_ = (L >> 2) & 1, h_ = (L >> 1) & 1, dl_ = L & 1;
    vkey0 = 16 * f_ + 8 * h_ + 4 * t_ + ((c & 7) >> 1);
    vd0 = ((db_ * 2 + dl_) << 4) + (c & 1) * 8;
  }
  {
    int c = tid + 256, L = c >> 3;
    int f_ = L >> 4, t_ = (L >> 3) & 1, db_ = (L >> 2) & 1, h_ = (L >> 1) & 1, dl_ = L & 1;
    vkey1 = 16 * f_ + 8 * h_ + 4 * t_ + ((c & 7) >> 1);
    vd1 = ((db_ * 2 + dl_) << 4) + (c & 1) * 8;
  }
  const bf16_t* srcV0 = qkv + (size_t)(tokb + kb0 + vkey0) * 3072 + 2048 + (size_t)h * 64 + vd0;
  const bf16_t* srcV1 = qkv + (size_t)(tokb + kb0 + vkey1) * 3072 + 2048 + (size_t)h * 64 + vd1;
  const int krow0 = ((w * 2 + 0) * 8) + (lane >> 3);
  const int krow1 = ((w * 2 + 1) * 8) + (lane >> 3);
  const bf16_t* srcK0 = qkv + (size_t)(tokb + kb0 + krow0) * 3072 + 1024 + (size_t)h * 64
                        + (((lane & 7) ^ (krow0 & 7)) * 8);
  const bf16_t* srcK1 = qkv + (size_t)(tokb + kb0 + krow1) * 3072 + 1024 + (size_t)h * 64
                        + (((lane & 7) ^ (krow1 & 7)) * 8);
  const int* mptr = mask + tokb + kb0 + lane;

#define STAGE_K(buf)                                                                  \
  {                                                                                   \
    ASYNC_COPY16(&Kl[buf][(w * 2 + 0) * 8][0], srcK0);                                \
    ASYNC_COPY16(&Kl[buf][(w * 2 + 1) * 8][0], srcK1);                                \
    srcK0 += 64 * 3072;                                                               \
    srcK1 += 64 * 3072;                                                               \
  }

#define STAGE_V(buf)                                                                  \
  {                                                                                   \
    ASYNC_COPY16(Vl0 + (size_t)(buf) * 4096 + (size_t)wbase * 8, srcV0);              \
    ASYNC_COPY16(Vl0 + (size_t)(buf) * 4096 + (size_t)(256 + wbase) * 8, srcV1);      \
    srcV0 += 64 * 3072;                                                               \
    srcV1 += 64 * 3072;                                                               \
  }

  // per-wave mask state in registers: each wave loads mask[key=lane] for the tile.
  float mreg_cur, mreg_nxt;
  bool allv_cur, allv_nxt;
  {
    mreg_cur = (*mptr) ? 1.f : 0.f;
    mptr += 64;
    unsigned long long z = __ballot(mreg_cur == 0.f);
    allv_cur = (z == 0ull);
  }

  // ---- prologue ----
  STAGE_K(0)
  STAGE_V(0)

  f32x16 o[2];
#pragma unroll
  for (int d = 0; d < 2; ++d)
#pragma unroll
    for (int i = 0; i < 16; ++i) o[d][i] = 0.f;
  float psum = 0.f;

  __syncthreads();

  for (int kt = 0; kt < SEQC / 128; ++kt) {   // 16 tiles of 64 keys
    const int cur = kt & 1, nxt = cur ^ 1;
    const bool more = (kt < SEQC / 128 - 1);

    if (more) {
      STAGE_K(nxt)
      STAGE_V(nxt)
      mreg_nxt = (*mptr) ? 1.f : 0.f;
      mptr += 64;
      unsigned long long z = __ballot(mreg_nxt == 0.f);
      allv_nxt = (z == 0ull);
    }

    // swapped QK^T
    f32x16 st[2];
#pragma unroll
    for (int kk = 0; kk < 2; ++kk)
#pragma unroll
      for (int i = 0; i < 16; ++i) st[kk][i] = 0.f;
    __builtin_amdgcn_s_setprio(1);
#pragma unroll
    for (int step = 0; step < 4; ++step) {
#pragma unroll
      for (int kb2 = 0; kb2 < 2; ++kb2) {
        int key = kb2 * 32 + l31;
        int seg = (2 * step + hi) ^ (lane & 7);
        s16x8 kf = *(const s16x8*)(klc + cur * 8192 + key * 128 + seg * 16);
        st[kb2] = __builtin_amdgcn_mfma_f32_32x32x16_bf16(kf, qfrag[step], st[kb2], 0, 0, 0);
      }
    }
    __builtin_amdgcn_s_setprio(0);

    // softmax (lane-local) + pack via cvt_pk + permlane32_swap
    s16x8 pf[4];
#pragma unroll
    for (int kb2 = 0; kb2 < 2; ++kb2) {
      float pa[16];
      if (allv_cur) {
#pragma unroll
        for (int i = 0; i < 16; ++i) {
          float e = __builtin_exp2f(st[kb2][i]);
          pa[i] = e;
          psum += e;
        }
      } else {
        // cold path: mask value for reg (g,rr) lives at lane key = rr+8g+4hi+32kb2
#pragma unroll
        for (int g = 0; g < 4; ++g)
#pragma unroll
          for (int rr = 0; rr < 4; ++rr) {
            float mmv = __shfl(mreg_cur, rr + 8 * g + 4 * hi + 32 * kb2);
            float e = __builtin_exp2f(st[kb2][g * 4 + rr]) * mmv;
            pa[g * 4 + rr] = e;
            psum += e;
          }
      }
      unsigned int wv[8];
#pragma unroll
      for (int u = 0; u < 8; ++u) wv[u] = cvt_pk_bf16(pa[2 * u], pa[2 * u + 1]);
      unsigned int a0 = wv[0], b0 = wv[2]; PSWAP(a0, b0);
      unsigned int a1 = wv[1], b1 = wv[3]; PSWAP(a1, b1);
      unsigned int a2 = wv[4], b2 = wv[6]; PSWAP(a2, b2);
      unsigned int a3 = wv[5], b3 = wv[7]; PSWAP(a3, b3);
      uint4 u0 = {a0, a1, b0, b1};
      uint4 u1 = {a2, a3, b2, b3};
      pf[kb2 * 2 + 0] = __builtin_bit_cast(s16x8, u0);
      pf[kb2 * 2 + 1] = __builtin_bit_cast(s16x8, u1);
    }

    // PV per d-block: batch 8 tr_reads, wait, 4 MFMA
    const unsigned va = vbase + cur * 8192;
#pragma unroll
    for (int db = 0; db < 2; ++db) {
      ulong tr[4][2];
#pragma unroll
      for (int f = 0; f < 4; ++f)
        asm volatile("ds_read_b64_tr_b16 %0, %2 offset:%c3\n\t"
                     "ds_read_b64_tr_b16 %1, %2 offset:%c4"
                     : "=v"(tr[f][0]), "=v"(tr[f][1])
                     : "v"(va), "i"((f * 16 + db * 4) * 128), "i"((f * 16 + 8 + db * 4) * 128));
      asm volatile("s_waitcnt lgkmcnt(0)" ::: "memory");
      __builtin_amdgcn_sched_barrier(0);
      __builtin_amdgcn_s_setprio(1);
#pragma unroll
      for (int f = 0; f < 4; ++f) {
        ulong2 uv = {tr[f][0], tr[f][1]};
        s16x8 vfr = __builtin_bit_cast(s16x8, uv);
        o[db] = __builtin_amdgcn_mfma_f32_32x32x16_bf16(pf[f], vfr, o[db], 0, 0, 0);
      }
      __builtin_amdgcn_s_setprio(0);
    }

    if (more) {
      mreg_cur = mreg_nxt;
      allv_cur = allv_nxt;
    }
    __syncthreads();
  }

  // ---- write unnormalized partials (bf16; merge renormalizes in f32) ----
  psum += __shfl_xor(psum, 32);
  bf16_t* po = half ? pB : pA;
  float* ps = half ? psB : psA;
#pragma unroll
  for (int dblk = 0; dblk < 2; ++dblk)
#pragma unroll
    for (int r = 0; r < 16; ++r) {
      int qq = (r & 3) + 8 * (r >> 2) + 4 * hi;
      int tok = tokb + q0 + qq;
      po[(size_t)tok * 1024 + h * 64 + dblk * 32 + l31] = __float2bfloat16(o[dblk][r]);
    }
  if (hi == 0)
    ps[(size_t)(tokb + q0 + l31) * 16 + h] = psum;
#undef STAGE_K
#undef STAGE_V
}

// ---------------- attention merge: ctx = (pA+pB) / (psA+psB) -> bf16 ----------------
__global__ __launch_bounds__(256) void k_attn_merge(
    const bf16_t* __restrict__ pA, const bf16_t* __restrict__ pB,
    const float* __restrict__ psA, const float* __restrict__ psB,
    bf16_t* __restrict__ ctx) {
  const int row = blockIdx.x, tid = threadIdx.x;
  const size_t base = (size_t)row * 1024;
  const short4 a4 = ((const short4*)(pA + base))[tid];
  const short4 b4 = ((const short4*)(pB + base))[tid];
  const int hh = tid >> 4;
  const float rs = psA[row * 16 + hh] + psB[row * 16 + hh];
  const float inv = 1.f / rs;
  const bf16_t* ae = (const bf16_t*)&a4;
  const bf16_t* be = (const bf16_t*)&b4;
  short4 ob;
  short* oe = (short*)&ob;
#pragma unroll
  for (int i = 0; i < 4; ++i)
    oe[i] = (short)f2bf_u16((__bfloat162float(ae[i]) + __bfloat162float(be[i])) * inv);
  ((short4*)(ctx + base))[tid] = ob;
}

// ---------------- fused split-K reduce + bias + residual + layernorm ----------------
__global__ __launch_bounds__(256) void k_ln_res2(
    const float* __restrict__ p0, const float* __restrict__ p1,
    const float* __restrict__ res, const float* __restrict__ bias,
    const float* __restrict__ g, const float* __restrict__ be,
    float* __restrict__ outf, bf16_t* __restrict__ outh) {
  const int row = blockIdx.x, tid = threadIdx.x;
  const size_t base = (size_t)row * D_MODELC;
  const float4 a  = ((const float4*)(p0 + base))[tid];
  const float4 bq = ((const float4*)(p1 + base))[tid];
  const float4 c  = ((const float4*)(res + base))[tid];
  const float4 bi = ((const float4*)bias)[tid];
  float4 v;
  v.x = a.x + bq.x + c.x + bi.x;
  v.y = a.y + bq.y + c.y + bi.y;
  v.z = a.z + bq.z + c.z + bi.z;
  v.w = a.w + bq.w + c.w + bi.w;
  float s1 = v.x + v.y + v.z + v.w;
  float s2 = v.x * v.x + v.y * v.y + v.z * v.z + v.w * v.w;
#pragma unroll
  for (int mm = 1; mm < 64; mm <<= 1) {
    s1 += __shfl_xor(s1, mm);
    s2 += __shfl_xor(s2, mm);
  }
  __shared__ float sa[4], sb[4];
  const int wv = tid >> 6;
  if ((tid & 63) == 0) { sa[wv] = s1; sb[wv] = s2; }
  __syncthreads();
  s1 = sa[0] + sa[1] + sa[2] + sa[3];
  s2 = sb[0] + sb[1] + sb[2] + sb[3];
  const float mu = s1 * (1.f / D_MODELC);
  const float var = s2 * (1.f / D_MODELC) - mu * mu;
  const float rsq = rsqrtf(var + 1e-5f);
  const float4 gg = ((const float4*)g)[tid];
  const float4 bb = ((const float4*)be)[tid];
  float4 oo;
  oo.x = (v.x - mu) * rsq * gg.x + bb.x;
  oo.y = (v.y - mu) * rsq * gg.y + bb.y;
  oo.z = (v.z - mu) * rsq * gg.z + bb.z;
  oo.w = (v.w - mu) * rsq * gg.w + bb.w;
  ((float4*)(outf + base))[tid] = oo;
  if (outh) {
    short4 ob;
    ob.x = (short)f2bf_u16(oo.x);
    ob.y = (short)f2bf_u16(oo.y);
    ob.z = (short)f2bf_u16(oo.z);
    ob.w = (short)f2bf_u16(oo.w);
    ((short4*)(outh + base))[tid] = ob;
  }
}

extern "C" void kernel_launch(void* const* d_in, const int* in_sizes, int n_in,
                              void* d_out, int out_size, void* d_ws, size_t ws_size,
                              hipStream_t stream) {
  (void)in_sizes; (void)n_in; (void)out_size; (void)ws_size;
  const float* x   = (const float*)d_in[0];
  const int* mask  = (const int*)d_in[1];
  const float* Wq  = (const float*)d_in[2];
  const float* bq  = (const float*)d_in[3];
  const float* Wk  = (const float*)d_in[4];
  const float* bk  = (const float*)d_in[5];
  const float* Wv  = (const float*)d_in[6];
  const float* bv  = (const float*)d_in[7];
  const float* Wo  = (const float*)d_in[8];
  const float* bo  = (const float*)d_in[9];
  const float* W1  = (const float*)d_in[10];
  const float* b1  = (const float*)d_in[11];
  const float* W2  = (const float*)d_in[12];
  const float* b2  = (const float*)d_in[13];
  const float* g1  = (const float*)d_in[14];
  const float* be1 = (const float*)d_in[15];
  const float* g2  = (const float*)d_in[16];
  const float* be2 = (const float*)d_in[17];

  char* ws = (char*)d_ws;
  const size_t D = D_MODELC, F = D_FFC, M = M_TOK;
  const size_t SZ_X16  = M * D * 2;
  const size_t SZ_QKV  = M * 3 * D * 2;
  bf16_t* x16   = (bf16_t*)ws;
  bf16_t* ff1   = (bf16_t*)ws;             // aliases x16+qkv (both dead by FF1)
  bf16_t* qkvb  = (bf16_t*)(ws + SZ_X16);
  size_t off = SZ_X16 + SZ_QKV;
  bf16_t* ctx   = (bf16_t*)(ws + off); off += M * D * 2;
  bf16_t* wqkvT = (bf16_t*)(ws + off); off += 3 * D * D * 2;
  bf16_t* woT   = (bf16_t*)(ws + off); off += D * D * 2;
  bf16_t* w1T   = (bf16_t*)(ws + off); off += D * F * 2;
  bf16_t* w2T   = (bf16_t*)(ws + off); off += D * F * 2;
  float*  partA = (float*)(ws + off);  off += M * D * 4;   // f32 split-K p0 / attn pA (bf16)
  float*  hbuf  = (float*)(ws + off);  off += M * D * 4;
  bf16_t* h16   = (bf16_t*)(ws + off); off += M * D * 2;
  float*  partB = (float*)(ws + off);  off += M * D * 4;   // f32 split-K p1 / attn pB (bf16)
  float*  bqkv  = (float*)(ws + off);  off += 3 * D * 4;
  float*  psA   = (float*)(ws + off);  off += M * 16 * 4;
  float*  psB   = (float*)(ws + off);  off += M * 16 * 4;

  // --- fused prep ---
  k_prep<<<16396, 256, 0, stream>>>(x, Wq, Wk, Wv, Wo, W1, W2, bq, bk, bv,
                                    x16, wqkvT, woT, w1T, w2T, bqkv);

  // --- QKV projection: 256^2 deep-pipelined (192 blocks) ---
  k_gemm256<<<192, 512, 0, stream>>>(x16, wqkvT, bqkv, qkvb,
                                     3072, 1024, 1024, 1024, 3072, 3);

  // --- attention: K-split x2, XCD-grouped, 5 blocks/CU, bf16 partials ---
  k_attn<<<1024, 256, 0, stream>>>(qkvb, mask, (bf16_t*)partA, (bf16_t*)partB, psA, psB);
  k_attn_merge<<<4096, 256, 0, stream>>>((bf16_t*)partA, (bf16_t*)partB, psA, psB, ctx);

  // --- output projection, split-K=2 -> partials ---
  k_gemm<<<512, 256, 0, stream>>>(ctx, woT, nullptr, partA, partB, nullptr,
                                  4096, 1024, 512, 1024, 1024, 1024, 4, 2);
  k_ln_res2<<<4096, 256, 0, stream>>>(partA, partB, x, bo, g1, be1, hbuf, h16);

  // --- FFN: FF1 = 256^2 deep-pipelined (256 blocks), FF2 = 128^2 split-K ---
  k_gemm256<<<256, 512, 0, stream>>>(h16, w1T, b1, ff1,
                                     4096, 1024, 1024, 1024, 4096, 1);
  k_gemm<<<512, 256, 0, stream>>>(ff1, w2T, nullptr, partA, partB, nullptr,
                                  4096, 1024, 2048, 4096, 4096, 1024, 4, 2);
  k_ln_res2<<<4096, 256, 0, stream>>>(partA, partB, hbuf, b2, g2, be2, (float*)d_out, nullptr);
}

// Round 14
// 230.186 us; speedup vs baseline: 1.1503x; 1.1503x over previous
//
#include <hip/hip_runtime.h>
#include <hip/hip_bf16.h>

#define D_MODELC 1024
#define D_FFC    4096
#define N_HEADSC 16
#define BATCHC   2
#define SEQC     2048
#define M_TOK    (BATCHC*SEQC)   // 4096

typedef __attribute__((ext_vector_type(4)))  float f32x4;
typedef __attribute__((ext_vector_type(16))) float f32x16;
typedef __attribute__((ext_vector_type(8)))  short s16x8;
using bf16_t = __hip_bfloat16;

static __device__ __forceinline__ unsigned short f2bf_u16(float f) {
  bf16_t h = __float2bfloat16(f);
  return __builtin_bit_cast(unsigned short, h);
}

static __device__ __forceinline__ unsigned int cvt_pk_bf16(float lo, float hi2) {
  unsigned int r;
  asm("v_cvt_pk_bf16_f32 %0, %1, %2" : "=v"(r) : "v"(lo), "v"(hi2));
  return r;
}

#define PSWAP(a, b) asm volatile("v_permlane32_swap_b32 %0, %1" : "+v"(a), "+v"(b))

#define ASYNC_COPY16(dst_lds, src_g) \
  __builtin_amdgcn_global_load_lds((const __attribute__((address_space(1))) void*)(src_g), \
                                   (__attribute__((address_space(3))) void*)(dst_lds), 16, 0, 0)

// ---------------- fused prep: 4x 1024^2 transpose + W1^T + W2^T + x->bf16 + bias pack ----
__global__ __launch_bounds__(256) void k_prep(
    const float* __restrict__ x,
    const float* __restrict__ Wq, const float* __restrict__ Wk,
    const float* __restrict__ Wv, const float* __restrict__ Wo,
    const float* __restrict__ W1, const float* __restrict__ W2,
    const float* __restrict__ bq, const float* __restrict__ bk,
    const float* __restrict__ bv,
    bf16_t* __restrict__ x16, bf16_t* __restrict__ wqkvT, bf16_t* __restrict__ woT,
    bf16_t* __restrict__ w1T, bf16_t* __restrict__ w2T, float* __restrict__ bqkv) {
  __shared__ float tile[32][33];
  const int bidx = blockIdx.x;
  const int tid = threadIdx.x;

  if (bidx < 12288) {
    const float* in;
    bf16_t* out;
    int R, C, bx, by;
    if (bidx < 4096) {
      const int z = bidx >> 10, t = bidx & 1023;
      in = (z == 0) ? Wq : (z == 1) ? Wk : (z == 2) ? Wv : Wo;
      out = (z == 0) ? wqkvT : (z == 1) ? wqkvT + 1024 * 1024
           : (z == 2) ? wqkvT + 2 * 1024 * 1024 : woT;
      R = 1024; C = 1024; bx = t & 31; by = t >> 5;
    } else if (bidx < 8192) {
      const int t = bidx - 4096;
      in = W1; out = w1T; R = 1024; C = 4096; bx = t & 127; by = t >> 7;
    } else {
      const int t = bidx - 8192;
      in = W2; out = w2T; R = 4096; C = 1024; bx = t & 31; by = t >> 5;
    }
    const int tx = tid & 31, ty = tid >> 5;
    const int c0 = bx * 32, r0 = by * 32;
#pragma unroll
    for (int i = 0; i < 4; ++i)
      tile[ty + i * 8][tx] = in[(size_t)(r0 + ty + i * 8) * C + c0 + tx];
    __syncthreads();
#pragma unroll
    for (int i = 0; i < 4; ++i)
      out[(size_t)(c0 + ty + i * 8) * R + r0 + tx] = __float2bfloat16(tile[tx][ty + i * 8]);
  } else if (bidx < 16384) {
    const int i = (bidx - 12288) * 256 + tid;
    float4 v = ((const float4*)x)[i];
    short4 o;
    o.x = (short)f2bf_u16(v.x);
    o.y = (short)f2bf_u16(v.y);
    o.z = (short)f2bf_u16(v.z);
    o.w = (short)f2bf_u16(v.w);
    ((short4*)x16)[i] = o;
  } else {
    const int i = (bidx - 16384) * 256 + tid;
    float v = (i < 1024) ? bq[i] : (i < 2048) ? bk[i - 1024] : bv[i - 2048];
    bqkv[i] = v;
  }
}

// ---------------- GEMM 256x256, BK=64, deep pipeline w/ counted vmcnt (T3+T4+T5) --------
__global__ __launch_bounds__(512, 2) void k_gemm256(
    const bf16_t* __restrict__ A, const bf16_t* __restrict__ BT,
    const float* __restrict__ bias, bf16_t* __restrict__ Cout,
    int N, int K, int lda, int ldb, int ldc, int mode) {
  __shared__ __align__(16) bf16_t Ab[2][256][64];
  __shared__ __align__(16) bf16_t Bb[2][256][64];

  const int nbn = N / 256;
  const int nwg = gridDim.x;
  const int cpx = nwg >> 3;
  const int wg = (blockIdx.x & 7) * cpx + (blockIdx.x >> 3);  // XCD swizzle (nwg%8==0)
  const int mb = wg / nbn, nb = wg % nbn;
  const int row0 = mb * 256, col0 = nb * 256;

  const int tid = threadIdx.x;
  const int w = tid >> 6, lane = tid & 63;
  const int lr = lane & 15, lg = lane >> 4;
  const int wr = w >> 2, wc = w & 3;
  const int s7 = lr & 7;

#define STAGE256(buf, kt_)                                                            \
  {                                                                                   \
    const int k0_ = (kt_) * 64;                                                       \
    _Pragma("unroll")                                                                 \
    for (int i_ = 0; i_ < 4; ++i_) {                                                  \
      int c_ = tid + i_ * 512;                                                        \
      int row_ = c_ >> 3, sg_ = (c_ & 7) ^ (row_ & 7);                                \
      ASYNC_COPY16(&Ab[buf][0][0] + (size_t)c_ * 8,                                   \
                   A + (size_t)(row0 + row_) * lda + k0_ + sg_ * 8);                  \
    }                                                                                 \
    _Pragma("unroll")                                                                 \
    for (int i_ = 0; i_ < 4; ++i_) {                                                  \
      int c_ = tid + i_ * 512;                                                        \
      int row_ = c_ >> 3, sg_ = (c_ & 7) ^ (row_ & 7);                                \
      ASYNC_COPY16(&Bb[buf][0][0] + (size_t)c_ * 8,                                   \
                   BT + (size_t)(col0 + row_) * ldb + k0_ + sg_ * 8);                 \
    }                                                                                 \
  }

  f32x4 acc[8][4];
#pragma unroll
  for (int m = 0; m < 8; ++m)
#pragma unroll
    for (int n = 0; n < 4; ++n) acc[m][n] = (f32x4){0.f, 0.f, 0.f, 0.f};

  const int nt = K / 64;
  STAGE256(0, 0)
  STAGE256(1, 1)
  asm volatile("s_waitcnt vmcnt(8)" ::: "memory");
  __builtin_amdgcn_sched_barrier(0);
  __builtin_amdgcn_s_barrier();

  for (int t = 0; t < nt; ++t) {
    const int cur = t & 1;
    s16x8 a0[8], b0[4];
#pragma unroll
    for (int m = 0; m < 8; ++m)
      a0[m] = *(const s16x8*)(&Ab[cur][wr * 128 + m * 16 + lr][(lg ^ s7) * 8]);
#pragma unroll
    for (int n = 0; n < 4; ++n)
      b0[n] = *(const s16x8*)(&Bb[cur][wc * 64 + n * 16 + lr][(lg ^ s7) * 8]);
    __builtin_amdgcn_s_setprio(1);
#pragma unroll
    for (int m = 0; m < 8; ++m)
#pragma unroll
      for (int n = 0; n < 4; ++n)
        acc[m][n] = __builtin_amdgcn_mfma_f32_16x16x32_bf16(a0[m], b0[n], acc[m][n], 0, 0, 0);
    __builtin_amdgcn_s_setprio(0);
    s16x8 a1[8], b1[4];
#pragma unroll
    for (int m = 0; m < 8; ++m)
      a1[m] = *(const s16x8*)(&Ab[cur][wr * 128 + m * 16 + lr][((4 + lg) ^ s7) * 8]);
#pragma unroll
    for (int n = 0; n < 4; ++n)
      b1[n] = *(const s16x8*)(&Bb[cur][wc * 64 + n * 16 + lr][((4 + lg) ^ s7) * 8]);
    asm volatile("s_waitcnt lgkmcnt(0)" ::: "memory");
    __builtin_amdgcn_sched_barrier(0);
    __builtin_amdgcn_s_barrier();
    if (t + 2 < nt) STAGE256(cur, t + 2)
    __builtin_amdgcn_s_setprio(1);
#pragma unroll
    for (int m = 0; m < 8; ++m)
#pragma unroll
      for (int n = 0; n < 4; ++n)
        acc[m][n] = __builtin_amdgcn_mfma_f32_16x16x32_bf16(a1[m], b1[n], acc[m][n], 0, 0, 0);
    __builtin_amdgcn_s_setprio(0);
    if (t + 2 < nt) {
      asm volatile("s_waitcnt vmcnt(8)" ::: "memory");
    } else {
      asm volatile("s_waitcnt vmcnt(0)" ::: "memory");
    }
    __builtin_amdgcn_sched_barrier(0);
    __builtin_amdgcn_s_barrier();
  }

#pragma unroll
  for (int m = 0; m < 8; ++m) {
    int grow = row0 + wr * 128 + m * 16 + lg * 4;
#pragma unroll
    for (int n = 0; n < 4; ++n) {
      int gcol = col0 + wc * 64 + n * 16 + lr;
      float bv = bias[gcol];
      float cs = (mode == 3 && gcol < 1024) ? 0.18033688f : 1.f;  // 0.125*log2(e)
#pragma unroll
      for (int r = 0; r < 4; ++r) {
        float v = (acc[m][n][r] + bv) * cs;
        if (mode == 1) v = fmaxf(v, 0.f);
        Cout[(size_t)(grow + r) * ldc + gcol] = __float2bfloat16(v);
      }
    }
  }
#undef STAGE256
}

// ---------------- GEMM: 128x128 tile, BK=64, XOR-swizzled LDS, split-K (Wo/FF2) ---------
#define GBK 64

__global__ __launch_bounds__(256, 2) void k_gemm(
    const bf16_t* __restrict__ A, const bf16_t* __restrict__ BT,
    const float* __restrict__ bias,
    float* __restrict__ p0, float* __restrict__ p1,
    void* __restrict__ Cout, int M, int N, int K,
    int lda, int ldb, int ldc, int mode, int nsplit) {
  __shared__ __align__(16) bf16_t Asm[128 * GBK];
  __shared__ __align__(16) bf16_t Bsm[128 * GBK];

  const int nbn = N / 128;
  const int nwg = gridDim.x;
  const int cpx = nwg >> 3;
  int wg = (blockIdx.x & 7) * cpx + (blockIdx.x >> 3);  // XCD swizzle (nwg % 8 == 0)
  int kslice = 0;
  if (nsplit == 2) { kslice = wg & 1; wg >>= 1; }
  const int mb = wg / nbn, nb = wg % nbn;
  const int row0 = mb * 128, col0 = nb * 128;
  A  += (size_t)kslice * K;
  BT += (size_t)kslice * K;

  const int tid = threadIdx.x;
  const int w = tid >> 6, lane = tid & 63;
  const int lr = lane & 15, lg = lane >> 4;
  const int wr = w >> 1, wc = w & 1;
  const int wbase = tid & 192;

  f32x4 acc[4][4];
#pragma unroll
  for (int m = 0; m < 4; ++m)
#pragma unroll
    for (int n = 0; n < 4; ++n) acc[m][n] = (f32x4){0.f, 0.f, 0.f, 0.f};

  for (int k0 = 0; k0 < K; k0 += GBK) {
    __syncthreads();
#pragma unroll
    for (int i = 0; i < 4; ++i) {
      int c = i * 256 + tid;
      int row = c >> 3;
      int sg = (c & 7) ^ (row & 7);
      ASYNC_COPY16(Asm + (size_t)(i * 256 + wbase) * 8,
                   A + (size_t)(row0 + row) * lda + k0 + sg * 8);
    }
#pragma unroll
    for (int i = 0; i < 4; ++i) {
      int c = i * 256 + tid;
      int row = c >> 3;
      int sg = (c & 7) ^ (row & 7);
      ASYNC_COPY16(Bsm + (size_t)(i * 256 + wbase) * 8,
                   BT + (size_t)(col0 + row) * ldb + k0 + sg * 8);
    }
    __syncthreads();
#pragma unroll
    for (int kst = 0; kst < 2; ++kst) {
      const int sl = ((kst * 4 + lg) ^ (lr & 7)) * 8;
      s16x8 af[4], bfr[4];
#pragma unroll
      for (int m = 0; m < 4; ++m)
        af[m] = *(const s16x8*)(Asm + (size_t)(wr * 64 + m * 16 + lr) * GBK + sl);
#pragma unroll
      for (int n = 0; n < 4; ++n)
        bfr[n] = *(const s16x8*)(Bsm + (size_t)(wc * 64 + n * 16 + lr) * GBK + sl);
#pragma unroll
      for (int m = 0; m < 4; ++m)
#pragma unroll
        for (int n = 0; n < 4; ++n)
          acc[m][n] = __builtin_amdgcn_mfma_f32_16x16x32_bf16(af[m], bfr[n], acc[m][n], 0, 0, 0);
    }
  }

  float* outf = (kslice == 0) ? p0 : p1;
  bf16_t* outh = (bf16_t*)Cout;
#pragma unroll
  for (int m = 0; m < 4; ++m) {
    int grow = row0 + wr * 64 + m * 16 + lg * 4;
#pragma unroll
    for (int n = 0; n < 4; ++n) {
      int gcol = col0 + wc * 64 + n * 16 + lr;
      float bv = (mode == 4) ? 0.f : bias[gcol];
#pragma unroll
      for (int r = 0; r < 4; ++r) {
        float v = acc[m][n][r] + bv;
        size_t idx = (size_t)(grow + r) * ldc + gcol;
        if (mode == 4) {
          outf[idx] = v;
        } else {
          if (mode == 1) v = fmaxf(v, 0.f);
          outh[idx] = __float2bfloat16(v);
        }
      }
    }
  }
}

// ---------------- flash attention: 32x32 MFMA, K-split x2, bf16 partials ----------------
// XCD-group mapping: all 16 qt-blocks of one (half,b,h) group share blockIdx%8 (one XCD).
// Mask flag/values in registers. __launch_bounds__(256,4): the 5-wave cap spills
// (r13: VGPR 64->48, WRITE 21->76MB scratch, dur 68->105) - 4 is the no-spill point.
__global__ __launch_bounds__(256, 4) void k_attn(
    const bf16_t* __restrict__ qkv, const int* __restrict__ mask,
    bf16_t* __restrict__ pA, bf16_t* __restrict__ pB,
    float* __restrict__ psA, float* __restrict__ psB) {
  const int bid = blockIdx.x;
  // bid = (j&7) | (qt<<3) | ((j>>3)<<7), j = (half<<5)|(b<<4)|h
  const int j = (bid & 7) + ((bid >> 7) << 3);
  const int qt = (bid >> 3) & 15;
  const int h = j & 15;
  const int b = (j >> 4) & 1;
  const int half = j >> 5;
  const int tid = threadIdx.x;
  const int w = tid >> 6, lane = tid & 63;
  const int l31 = lane & 31, hi = lane >> 5;
  const int wbase = tid & 192;

  __shared__ __align__(16) bf16_t Kl[2][64][64];   // XOR-swizzled (seg ^= row&7), 16 KB
  __shared__ __align__(16) bf16_t Vl[2][4096];     // tr-subtiled V, 16 KB

  const int tokb = b * SEQC;
  const int q0 = qt * 128 + w * 32;
  const int kb0 = half * (SEQC / 2);

  s16x8 qfrag[4];
  {
    const bf16_t* qp = qkv + (size_t)(tokb + q0 + l31) * 3072 + h * 64 + hi * 8;
#pragma unroll
    for (int s = 0; s < 4; ++s) qfrag[s] = *(const s16x8*)(qp + s * 16);
  }

  char* klc = (char*)&Kl[0][0][0];
  bf16_t* Vl0 = &Vl[0][0];
  const unsigned vbase =
      (unsigned)(size_t)(__attribute__((address_space(3))) bf16_t*)Vl0 + lane * 8;

  // hoisted staging source pointers (advance 64 tokens per tile)
  int vkey0, vd0, vkey1, vd1;
  {
    int c = tid, L = c >> 3;
    int f_ = L >> 4, t_ = (L >> 3) & 1, db_ = (L >> 2) & 1, h_ = (L >> 1) & 1, dl_ = L & 1;
    vkey0 = 16 * f_ + 8 * h_ + 4 * t_ + ((c & 7) >> 1);
    vd0 = ((db_ * 2 + dl_) << 4) + (c & 1) * 8;
  }
  {
    int c = tid + 256, L = c >> 3;
    int f_ = L >> 4, t_ = (L >> 3) & 1, db_ = (L >> 2) & 1, h_ = (L >> 1) & 1, dl_ = L & 1;
    vkey1 = 16 * f_ + 8 * h_ + 4 * t_ + ((c & 7) >> 1);
    vd1 = ((db_ * 2 + dl_) << 4) + (c & 1) * 8;
  }
  const bf16_t* srcV0 = qkv + (size_t)(tokb + kb0 + vkey0) * 3072 + 2048 + (size_t)h * 64 + vd0;
  const bf16_t* srcV1 = qkv + (size_t)(tokb + kb0 + vkey1) * 3072 + 2048 + (size_t)h * 64 + vd1;
  const int krow0 = ((w * 2 + 0) * 8) + (lane >> 3);
  const int krow1 = ((w * 2 + 1) * 8) + (lane >> 3);
  const bf16_t* srcK0 = qkv + (size_t)(tokb + kb0 + krow0) * 3072 + 1024 + (size_t)h * 64
                        + (((lane & 7) ^ (krow0 & 7)) * 8);
  const bf16_t* srcK1 = qkv + (size_t)(tokb + kb0 + krow1) * 3072 + 1024 + (size_t)h * 64
                        + (((lane & 7) ^ (krow1 & 7)) * 8);
  const int* mptr = mask + tokb + kb0 + lane;

#define STAGE_K(buf)                                                                  \
  {                                                                                   \
    ASYNC_COPY16(&Kl[buf][(w * 2 + 0) * 8][0], srcK0);                                \
    ASYNC_COPY16(&Kl[buf][(w * 2 + 1) * 8][0], srcK1);                                \
    srcK0 += 64 * 3072;                                                               \
    srcK1 += 64 * 3072;                                                               \
  }

#define STAGE_V(buf)                                                                  \
  {                                                                                   \
    ASYNC_COPY16(Vl0 + (size_t)(buf) * 4096 + (size_t)wbase * 8, srcV0);              \
    ASYNC_COPY16(Vl0 + (size_t)(buf) * 4096 + (size_t)(256 + wbase) * 8, srcV1);      \
    srcV0 += 64 * 3072;                                                               \
    srcV1 += 64 * 3072;                                                               \
  }

  // per-wave mask state in registers
  float mreg_cur, mreg_nxt;
  bool allv_cur, allv_nxt;
  {
    mreg_cur = (*mptr) ? 1.f : 0.f;
    mptr += 64;
    unsigned long long z = __ballot(mreg_cur == 0.f);
    allv_cur = (z == 0ull);
  }

  // ---- prologue ----
  STAGE_K(0)
  STAGE_V(0)

  f32x16 o[2];
#pragma unroll
  for (int d = 0; d < 2; ++d)
#pragma unroll
    for (int i = 0; i < 16; ++i) o[d][i] = 0.f;
  float psum = 0.f;

  __syncthreads();

  for (int kt = 0; kt < SEQC / 128; ++kt) {   // 16 tiles of 64 keys
    const int cur = kt & 1, nxt = cur ^ 1;
    const bool more = (kt < SEQC / 128 - 1);

    if (more) {
      STAGE_K(nxt)
      STAGE_V(nxt)
      mreg_nxt = (*mptr) ? 1.f : 0.f;
      mptr += 64;
      unsigned long long z = __ballot(mreg_nxt == 0.f);
      allv_nxt = (z == 0ull);
    }

    // swapped QK^T
    f32x16 st[2];
#pragma unroll
    for (int kk = 0; kk < 2; ++kk)
#pragma unroll
      for (int i = 0; i < 16; ++i) st[kk][i] = 0.f;
    __builtin_amdgcn_s_setprio(1);
#pragma unroll
    for (int step = 0; step < 4; ++step) {
#pragma unroll
      for (int kb2 = 0; kb2 < 2; ++kb2) {
        int key = kb2 * 32 + l31;
        int seg = (2 * step + hi) ^ (lane & 7);
        s16x8 kf = *(const s16x8*)(klc + cur * 8192 + key * 128 + seg * 16);
        st[kb2] = __builtin_amdgcn_mfma_f32_32x32x16_bf16(kf, qfrag[step], st[kb2], 0, 0, 0);
      }
    }
    __builtin_amdgcn_s_setprio(0);

    // softmax (lane-local) + pack via cvt_pk + permlane32_swap
    s16x8 pf[4];
#pragma unroll
    for (int kb2 = 0; kb2 < 2; ++kb2) {
      float pa[16];
      if (allv_cur) {
#pragma unroll
        for (int i = 0; i < 16; ++i) {
          float e = __builtin_exp2f(st[kb2][i]);
          pa[i] = e;
          psum += e;
        }
      } else {
        // cold path: mask value for reg (g,rr) lives at lane key = rr+8g+4hi+32kb2
#pragma unroll
        for (int g = 0; g < 4; ++g)
#pragma unroll
          for (int rr = 0; rr < 4; ++rr) {
            float mmv = __shfl(mreg_cur, rr + 8 * g + 4 * hi + 32 * kb2);
            float e = __builtin_exp2f(st[kb2][g * 4 + rr]) * mmv;
            pa[g * 4 + rr] = e;
            psum += e;
          }
      }
      unsigned int wv[8];
#pragma unroll
      for (int u = 0; u < 8; ++u) wv[u] = cvt_pk_bf16(pa[2 * u], pa[2 * u + 1]);
      unsigned int a0 = wv[0], b0 = wv[2]; PSWAP(a0, b0);
      unsigned int a1 = wv[1], b1 = wv[3]; PSWAP(a1, b1);
      unsigned int a2 = wv[4], b2 = wv[6]; PSWAP(a2, b2);
      unsigned int a3 = wv[5], b3 = wv[7]; PSWAP(a3, b3);
      uint4 u0 = {a0, a1, b0, b1};
      uint4 u1 = {a2, a3, b2, b3};
      pf[kb2 * 2 + 0] = __builtin_bit_cast(s16x8, u0);
      pf[kb2 * 2 + 1] = __builtin_bit_cast(s16x8, u1);
    }

    // PV per d-block: batch 8 tr_reads, wait, 4 MFMA
    const unsigned va = vbase + cur * 8192;
#pragma unroll
    for (int db = 0; db < 2; ++db) {
      ulong tr[4][2];
#pragma unroll
      for (int f = 0; f < 4; ++f)
        asm volatile("ds_read_b64_tr_b16 %0, %2 offset:%c3\n\t"
                     "ds_read_b64_tr_b16 %1, %2 offset:%c4"
                     : "=v"(tr[f][0]), "=v"(tr[f][1])
                     : "v"(va), "i"((f * 16 + db * 4) * 128), "i"((f * 16 + 8 + db * 4) * 128));
      asm volatile("s_waitcnt lgkmcnt(0)" ::: "memory");
      __builtin_amdgcn_sched_barrier(0);
      __builtin_amdgcn_s_setprio(1);
#pragma unroll
      for (int f = 0; f < 4; ++f) {
        ulong2 uv = {tr[f][0], tr[f][1]};
        s16x8 vfr = __builtin_bit_cast(s16x8, uv);
        o[db] = __builtin_amdgcn_mfma_f32_32x32x16_bf16(pf[f], vfr, o[db], 0, 0, 0);
      }
      __builtin_amdgcn_s_setprio(0);
    }

    if (more) {
      mreg_cur = mreg_nxt;
      allv_cur = allv_nxt;
    }
    __syncthreads();
  }

  // ---- write unnormalized partials (bf16; merge renormalizes in f32) ----
  psum += __shfl_xor(psum, 32);
  bf16_t* po = half ? pB : pA;
  float* ps = half ? psB : psA;
#pragma unroll
  for (int dblk = 0; dblk < 2; ++dblk)
#pragma unroll
    for (int r = 0; r < 16; ++r) {
      int qq = (r & 3) + 8 * (r >> 2) + 4 * hi;
      int tok = tokb + q0 + qq;
      po[(size_t)tok * 1024 + h * 64 + dblk * 32 + l31] = __float2bfloat16(o[dblk][r]);
    }
  if (hi == 0)
    ps[(size_t)(tokb + q0 + l31) * 16 + h] = psum;
#undef STAGE_K
#undef STAGE_V
}

// ---------------- attention merge: ctx = (pA+pB) / (psA+psB) -> bf16 ----------------
__global__ __launch_bounds__(256) void k_attn_merge(
    const bf16_t* __restrict__ pA, const bf16_t* __restrict__ pB,
    const float* __restrict__ psA, const float* __restrict__ psB,
    bf16_t* __restrict__ ctx) {
  const int row = blockIdx.x, tid = threadIdx.x;
  const size_t base = (size_t)row * 1024;
  const short4 a4 = ((const short4*)(pA + base))[tid];
  const short4 b4 = ((const short4*)(pB + base))[tid];
  const int hh = tid >> 4;
  const float rs = psA[row * 16 + hh] + psB[row * 16 + hh];
  const float inv = 1.f / rs;
  const bf16_t* ae = (const bf16_t*)&a4;
  const bf16_t* be = (const bf16_t*)&b4;
  short4 ob;
  short* oe = (short*)&ob;
#pragma unroll
  for (int i = 0; i < 4; ++i)
    oe[i] = (short)f2bf_u16((__bfloat162float(ae[i]) + __bfloat162float(be[i])) * inv);
  ((short4*)(ctx + base))[tid] = ob;
}

// ---------------- fused split-K reduce + bias + residual + layernorm ----------------
__global__ __launch_bounds__(256) void k_ln_res2(
    const float* __restrict__ p0, const float* __restrict__ p1,
    const float* __restrict__ res, const float* __restrict__ bias,
    const float* __restrict__ g, const float* __restrict__ be,
    float* __restrict__ outf, bf16_t* __restrict__ outh) {
  const int row = blockIdx.x, tid = threadIdx.x;
  const size_t base = (size_t)row * D_MODELC;
  const float4 a  = ((const float4*)(p0 + base))[tid];
  const float4 bq = ((const float4*)(p1 + base))[tid];
  const float4 c  = ((const float4*)(res + base))[tid];
  const float4 bi = ((const float4*)bias)[tid];
  float4 v;
  v.x = a.x + bq.x + c.x + bi.x;
  v.y = a.y + bq.y + c.y + bi.y;
  v.z = a.z + bq.z + c.z + bi.z;
  v.w = a.w + bq.w + c.w + bi.w;
  float s1 = v.x + v.y + v.z + v.w;
  float s2 = v.x * v.x + v.y * v.y + v.z * v.z + v.w * v.w;
#pragma unroll
  for (int mm = 1; mm < 64; mm <<= 1) {
    s1 += __shfl_xor(s1, mm);
    s2 += __shfl_xor(s2, mm);
  }
  __shared__ float sa[4], sb[4];
  const int wv = tid >> 6;
  if ((tid & 63) == 0) { sa[wv] = s1; sb[wv] = s2; }
  __syncthreads();
  s1 = sa[0] + sa[1] + sa[2] + sa[3];
  s2 = sb[0] + sb[1] + sb[2] + sb[3];
  const float mu = s1 * (1.f / D_MODELC);
  const float var = s2 * (1.f / D_MODELC) - mu * mu;
  const float rsq = rsqrtf(var + 1e-5f);
  const float4 gg = ((const float4*)g)[tid];
  const float4 bb = ((const float4*)be)[tid];
  float4 oo;
  oo.x = (v.x - mu) * rsq * gg.x + bb.x;
  oo.y = (v.y - mu) * rsq * gg.y + bb.y;
  oo.z = (v.z - mu) * rsq * gg.z + bb.z;
  oo.w = (v.w - mu) * rsq * gg.w + bb.w;
  ((float4*)(outf + base))[tid] = oo;
  if (outh) {
    short4 ob;
    ob.x = (short)f2bf_u16(oo.x);
    ob.y = (short)f2bf_u16(oo.y);
    ob.z = (short)f2bf_u16(oo.z);
    ob.w = (short)f2bf_u16(oo.w);
    ((short4*)(outh + base))[tid] = ob;
  }
}

extern "C" void kernel_launch(void* const* d_in, const int* in_sizes, int n_in,
                              void* d_out, int out_size, void* d_ws, size_t ws_size,
                              hipStream_t stream) {
  (void)in_sizes; (void)n_in; (void)out_size; (void)ws_size;
  const float* x   = (const float*)d_in[0];
  const int* mask  = (const int*)d_in[1];
  const float* Wq  = (const float*)d_in[2];
  const float* bq  = (const float*)d_in[3];
  const float* Wk  = (const float*)d_in[4];
  const float* bk  = (const float*)d_in[5];
  const float* Wv  = (const float*)d_in[6];
  const float* bv  = (const float*)d_in[7];
  const float* Wo  = (const float*)d_in[8];
  const float* bo  = (const float*)d_in[9];
  const float* W1  = (const float*)d_in[10];
  const float* b1  = (const float*)d_in[11];
  const float* W2  = (const float*)d_in[12];
  const float* b2  = (const float*)d_in[13];
  const float* g1  = (const float*)d_in[14];
  const float* be1 = (const float*)d_in[15];
  const float* g2  = (const float*)d_in[16];
  const float* be2 = (const float*)d_in[17];

  char* ws = (char*)d_ws;
  const size_t D = D_MODELC, F = D_FFC, M = M_TOK;
  const size_t SZ_X16  = M * D * 2;
  const size_t SZ_QKV  = M * 3 * D * 2;
  bf16_t* x16   = (bf16_t*)ws;
  bf16_t* ff1   = (bf16_t*)ws;             // aliases x16+qkv (both dead by FF1)
  bf16_t* qkvb  = (bf16_t*)(ws + SZ_X16);
  size_t off = SZ_X16 + SZ_QKV;
  bf16_t* ctx   = (bf16_t*)(ws + off); off += M * D * 2;
  bf16_t* wqkvT = (bf16_t*)(ws + off); off += 3 * D * D * 2;
  bf16_t* woT   = (bf16_t*)(ws + off); off += D * D * 2;
  bf16_t* w1T   = (bf16_t*)(ws + off); off += D * F * 2;
  bf16_t* w2T   = (bf16_t*)(ws + off); off += D * F * 2;
  float*  partA = (float*)(ws + off);  off += M * D * 4;   // f32 split-K p0 / attn pA (bf16)
  float*  hbuf  = (float*)(ws + off);  off += M * D * 4;
  bf16_t* h16   = (bf16_t*)(ws + off); off += M * D * 2;
  float*  partB = (float*)(ws + off);  off += M * D * 4;   // f32 split-K p1 / attn pB (bf16)
  float*  bqkv  = (float*)(ws + off);  off += 3 * D * 4;
  float*  psA   = (float*)(ws + off);  off += M * 16 * 4;
  float*  psB   = (float*)(ws + off);  off += M * 16 * 4;

  // --- fused prep ---
  k_prep<<<16396, 256, 0, stream>>>(x, Wq, Wk, Wv, Wo, W1, W2, bq, bk, bv,
                                    x16, wqkvT, woT, w1T, w2T, bqkv);

  // --- QKV projection: 256^2 deep-pipelined (192 blocks) ---
  k_gemm256<<<192, 512, 0, stream>>>(x16, wqkvT, bqkv, qkvb,
                                     3072, 1024, 1024, 1024, 3072, 3);

  // --- attention: K-split x2, XCD-grouped, bf16 partials ---
  k_attn<<<1024, 256, 0, stream>>>(qkvb, mask, (bf16_t*)partA, (bf16_t*)partB, psA, psB);
  k_attn_merge<<<4096, 256, 0, stream>>>((bf16_t*)partA, (bf16_t*)partB, psA, psB, ctx);

  // --- output projection, split-K=2 -> partials ---
  k_gemm<<<512, 256, 0, stream>>>(ctx, woT, nullptr, partA, partB, nullptr,
                                  4096, 1024, 512, 1024, 1024, 1024, 4, 2);
  k_ln_res2<<<4096, 256, 0, stream>>>(partA, partB, x, bo, g1, be1, hbuf, h16);

  // --- FFN: FF1 = 256^2 deep-pipelined (256 blocks), FF2 = 128^2 split-K ---
  k_gemm256<<<256, 512, 0, stream>>>(h16, w1T, b1, ff1,
                                     4096, 1024, 1024, 1024, 4096, 1);
  k_gemm<<<512, 256, 0, stream>>>(ff1, w2T, nullptr, partA, partB, nullptr,
                                  4096, 1024, 2048, 4096, 4096, 1024, 4, 2);
  k_ln_res2<<<4096, 256, 0, stream>>>(partA, partB, hbuf, b2, g2, be2, (float*)d_out, nullptr);
}